// Round 12
// baseline (967.803 us; speedup 1.0000x reference)
//
#include <hip/hip_runtime.h>
#include <hip/hip_bf16.h>

#define BB   16
#define SS   8192
#define DD   128
#define HH   256
#define NTOK (BB * SS)
#define TM   64
#define THREADS 256
#define LRATE 0.1f
#define EPSV  1e-5f
#define XST  136   // Xext stride in shorts (68 dw ≡ 4 mod 32, proven conflict-light)
#define HST  264   // Hb stride in shorts (132 dw ≡ 4 mod 32)

typedef short  bfrag __attribute__((ext_vector_type(8)));   // 8 bf16 = 4 VGPR (MFMA A/B frag)
typedef float  f32x4 __attribute__((ext_vector_type(4)));   // MFMA C/D frag
typedef unsigned short u16;

__device__ __forceinline__ u16 f2bf(float x) {
    unsigned u = __float_as_uint(x);
    unsigned r = (u + 0x7FFFu + ((u >> 16) & 1u)) >> 16;   // RTN-even
    return (u16)r;
}

// packed 2xfloat -> 2xbf16 (v_cvt_pk_bf16_f32, RNE)
__device__ __forceinline__ unsigned pkbf(float lo, float hi) {
    __hip_bfloat162 h2 = __float22bfloat162_rn(make_float2(lo, hi));
    unsigned u; __builtin_memcpy(&u, &h2, 4); return u;
}

// ---- weight prep: fp32 [K][N] -> bf16 transposed [N][K] in ws ----
// layout (shorts): W1t[256][128] @0, W2t[128][256] @32768, Wg1t[256][256] @65536 (k>=128 half scaled by 0.5),
//                  Wg2t[128][256] @131072
__global__ void prep_weights(const float* __restrict__ W1, const float* __restrict__ W2,
                             const float* __restrict__ Wg1, const float* __restrict__ Wg2,
                             u16* __restrict__ wsw) {
    int i = blockIdx.x * 256 + threadIdx.x;   // 0 .. 163839
    if (i < 32768) { int n = i >> 7, k = i & 127; wsw[i] = f2bf(W1[k * 256 + n]); return; }
    i -= 32768;
    if (i < 32768) { int n = i >> 8, k = i & 255; wsw[32768 + n * 256 + k] = f2bf(W2[k * 128 + n]); return; }
    i -= 32768;
    if (i < 65536) {
        int n = i >> 8, k = i & 255;
        const float s = (k >= 128) ? 0.5f : 1.0f;            // fold context average into weights
        wsw[65536 + n * 256 + k] = f2bf(Wg1[k * 256 + n] * s);
        return;
    }
    i -= 65536;
    { int n = i >> 8, k = i & 255; wsw[131072 + n * 256 + k] = f2bf(Wg2[k * 128 + n]); }
}

__global__ __launch_bounds__(THREADS, 3)
void refine_iter(const float* __restrict__ cur, const float* __restrict__ emb,
                 float* __restrict__ outp,
                 const u16* __restrict__ w1t, const u16* __restrict__ w2t,
                 const u16* __restrict__ wg1t, const u16* __restrict__ wg2t,
                 const float* __restrict__ b1, const float* __restrict__ lng,
                 const float* __restrict__ lnb, const float* __restrict__ b2,
                 const float* __restrict__ bg1, const float* __restrict__ bg2)
{
    __shared__ __align__(16) u16 Xext[TM + 2][XST];  // rows g0-1 .. g0+64, bf16
    __shared__ __align__(16) u16 Hb[TM][HST];        // H (phase-B input) then R (phase-D input)
    __shared__ float red1[TM][4];
    __shared__ float red2[TM][4];

    const int t    = threadIdx.x;
    const int g0   = blockIdx.x * TM;
    const int lane = t & 63;
    const int wid  = t >> 6;              // 4 waves; each owns ALL 64 rows x a column slice
    const int l16  = lane & 15;
    const int lk8  = (lane >> 4) * 8;     // k-offset within a 32-chunk
    const int l4   = (lane >> 4) * 4;     // D-frag row offset
    const int nAC  = wid * 64;            // A/C col slice (64 wide, ct 0..3)
    const int nBD  = wid * 32;            // B/D col slice (32 wide, ct 0..1)

    // ---- early prefetch: emb values needed by phase B (acc layout) ----
    float ep[4][2][4];
    #pragma unroll
    for (int rt = 0; rt < 4; ++rt)
        #pragma unroll
        for (int ct = 0; ct < 2; ++ct)
            #pragma unroll
            for (int r = 0; r < 4; ++r)
                ep[rt][ct][r] = emb[(size_t)(g0 + rt * 16 + l4 + r) * DD + nBD + ct * 16 + l16];

    // ---- stage Xext rows g0-1 .. g0+64 (fp32 -> bf16, packed cvt) ----
    // 66 rows x 32 float4-slots = 2112 slots
    {
        const int b13 = g0 & ~(SS - 1);   // batch base token
        const int s0  = g0 & (SS - 1);
        #pragma unroll
        for (int k = 0; k < 9; ++k) {
            const int f = t + k * THREADS;
            if (f < (TM + 2) * 32) {
                const int j = f >> 5;             // row 0..65
                const int o = (f & 31) * 4;
                int sraw = s0 + j - 1;
                const int s = (sraw < 0) ? 1 : ((sraw > SS - 1) ? (SS - 2) : sraw);
                const float4 xv = *(const float4*)(cur + (size_t)(b13 + s) * DD + o);
                uint2 xq; xq.x = pkbf(xv.x, xv.y); xq.y = pkbf(xv.z, xv.w);
                *(uint2*)&Xext[j][o] = xq;
            }
        }
    }
    __syncthreads();

    const f32x4 zf = {0.f, 0.f, 0.f, 0.f};
    float mu[4][4], rs[4][4];

    // ================= Phase A: Y1 = X @ W1 + b1  (64x256, K=128) =================
    {
        f32x4 acc[4][4];   // [rt][ct]
        #pragma unroll
        for (int rt = 0; rt < 4; ++rt)
            #pragma unroll
            for (int ct = 0; ct < 4; ++ct) acc[rt][ct] = zf;
        #pragma unroll
        for (int h = 0; h < 2; ++h) {        // ct-pairs
            bfrag wb[8];                     // i(2) x ks(4), batched
            #pragma unroll
            for (int i = 0; i < 2; ++i)
                #pragma unroll
                for (int ks = 0; ks < 4; ++ks)
                    wb[i * 4 + ks] = *(const bfrag*)(w1t + (size_t)(nAC + (h * 2 + i) * 16 + l16) * 128 + ks * 32 + lk8);
            __builtin_amdgcn_sched_barrier(0);
            #pragma unroll
            for (int ks = 0; ks < 4; ++ks) {
                bfrag af[4];
                #pragma unroll
                for (int rt = 0; rt < 4; ++rt)
                    af[rt] = *(const bfrag*)&Xext[rt * 16 + l16 + 1][ks * 32 + lk8];
                #pragma unroll
                for (int i = 0; i < 2; ++i)
                    #pragma unroll
                    for (int rt = 0; rt < 4; ++rt)
                        acc[rt][h * 2 + i] = __builtin_amdgcn_mfma_f32_16x16x32_bf16(af[rt], wb[i * 4 + ks], acc[rt][h * 2 + i], 0, 0, 0);
            }
        }
        // bias before LN stats
        #pragma unroll
        for (int ct = 0; ct < 4; ++ct) {
            const float bb = b1[nAC + ct * 16 + l16];
            #pragma unroll
            for (int rt = 0; rt < 4; ++rt)
                #pragma unroll
                for (int r = 0; r < 4; ++r) acc[rt][ct][r] += bb;
        }

        // ---- LN stats: 16-lane butterfly per row, cross-wave via red ----
        #pragma unroll
        for (int rt = 0; rt < 4; ++rt)
            #pragma unroll
            for (int r = 0; r < 4; ++r) {
                float a = 0.f, q = 0.f;
                #pragma unroll
                for (int ct = 0; ct < 4; ++ct) {
                    const float v = acc[rt][ct][r];
                    a += v; q += v * v;
                }
                #pragma unroll
                for (int m = 1; m <= 8; m <<= 1) {
                    a += __shfl_xor(a, m);
                    q += __shfl_xor(q, m);
                }
                if (l16 == 0) {
                    red1[rt * 16 + l4 + r][wid] = a;
                    red2[rt * 16 + l4 + r][wid] = q;
                }
            }
        __syncthreads();
        #pragma unroll
        for (int rt = 0; rt < 4; ++rt)
            #pragma unroll
            for (int r = 0; r < 4; ++r) {
                const int row = rt * 16 + l4 + r;
                const float4 s1v = *(const float4*)&red1[row][0];
                const float4 s2v = *(const float4*)&red2[row][0];
                const float s1 = s1v.x + s1v.y + s1v.z + s1v.w;
                const float s2 = s2v.x + s2v.y + s2v.z + s2v.w;
                const float m_ = s1 * (1.f / (float)HH);
                mu[rt][r] = m_;
                rs[rt][r] = rsqrtf(s2 * (1.f / (float)HH) - m_ * m_ + EPSV);
            }

        // ---- normalize + affine + relu -> Hb (bf16, packed cvt per ct-pair) ----
        #pragma unroll
        for (int cp2 = 0; cp2 < 2; ++cp2) {
            const float g0v = lng[nAC + (2 * cp2) * 16 + l16],     b0v = lnb[nAC + (2 * cp2) * 16 + l16];
            const float g1v = lng[nAC + (2 * cp2 + 1) * 16 + l16], b1v = lnb[nAC + (2 * cp2 + 1) * 16 + l16];
            #pragma unroll
            for (int rt = 0; rt < 4; ++rt)
                #pragma unroll
                for (int r = 0; r < 4; ++r) {
                    const float h0 = fmaxf((acc[rt][2 * cp2][r]     - mu[rt][r]) * rs[rt][r] * g0v + b0v, 0.f);
                    const float h1 = fmaxf((acc[rt][2 * cp2 + 1][r] - mu[rt][r]) * rs[rt][r] * g1v + b1v, 0.f);
                    const unsigned p = pkbf(h0, h1);
                    Hb[rt * 16 + l4 + r][nAC + (2 * cp2) * 16 + l16]     = (u16)(p & 0xffffu);
                    Hb[rt * 16 + l4 + r][nAC + (2 * cp2 + 1) * 16 + l16] = (u16)(p >> 16);
                }
        }
    }
    __syncthreads();

    // ================= Phase B: P = H @ W2 + b2 ; err = emb - P  (64x128, K=256) =================
    float errv[4][2][4];
    {
        f32x4 acc[4][2];
        #pragma unroll
        for (int rt = 0; rt < 4; ++rt) { acc[rt][0] = zf; acc[rt][1] = zf; }
        bfrag wb[16];                        // ct(2) x ks(8), batched
        #pragma unroll
        for (int ct = 0; ct < 2; ++ct)
            #pragma unroll
            for (int ks = 0; ks < 8; ++ks)
                wb[ct * 8 + ks] = *(const bfrag*)(w2t + (size_t)(nBD + ct * 16 + l16) * 256 + ks * 32 + lk8);
        __builtin_amdgcn_sched_barrier(0);
        #pragma unroll
        for (int ks = 0; ks < 8; ++ks) {
            bfrag af[4];
            #pragma unroll
            for (int rt = 0; rt < 4; ++rt)
                af[rt] = *(const bfrag*)&Hb[rt * 16 + l16][ks * 32 + lk8];
            #pragma unroll
            for (int ct = 0; ct < 2; ++ct)
                #pragma unroll
                for (int rt = 0; rt < 4; ++rt)
                    acc[rt][ct] = __builtin_amdgcn_mfma_f32_16x16x32_bf16(af[rt], wb[ct * 8 + ks], acc[rt][ct], 0, 0, 0);
        }
        #pragma unroll
        for (int ct = 0; ct < 2; ++ct) {
            const float bb = b2[nBD + ct * 16 + l16];
            #pragma unroll
            for (int rt = 0; rt < 4; ++rt)
                #pragma unroll
                for (int r = 0; r < 4; ++r)
                    errv[rt][ct][r] = ep[rt][ct][r] - (acc[rt][ct][r] + bb);
        }
    }

    // ===== Phase C: R = relu(X@Wg1a + Xprev@Wg1b' + Xnext@Wg1b' + bg1)  (Wg1b' pre-scaled 0.5) =====
    {
        f32x4 acc[4][4];
        #pragma unroll
        for (int rt = 0; rt < 4; ++rt)
            #pragma unroll
            for (int ct = 0; ct < 4; ++ct) acc[rt][ct] = zf;
        #pragma unroll
        for (int h = 0; h < 2; ++h) {        // ct-pairs
            // --- X part: k 0..127 ---
            bfrag wa[8];                     // i(2) x ks(4)
            #pragma unroll
            for (int i = 0; i < 2; ++i)
                #pragma unroll
                for (int ks = 0; ks < 4; ++ks)
                    wa[i * 4 + ks] = *(const bfrag*)(wg1t + (size_t)(nAC + (h * 2 + i) * 16 + l16) * 256 + ks * 32 + lk8);
            __builtin_amdgcn_sched_barrier(0);
            #pragma unroll
            for (int ks = 0; ks < 4; ++ks) {
                bfrag af[4];
                #pragma unroll
                for (int rt = 0; rt < 4; ++rt)
                    af[rt] = *(const bfrag*)&Xext[rt * 16 + l16 + 1][ks * 32 + lk8];
                #pragma unroll
                for (int i = 0; i < 2; ++i)
                    #pragma unroll
                    for (int rt = 0; rt < 4; ++rt)
                        acc[rt][h * 2 + i] = __builtin_amdgcn_mfma_f32_16x16x32_bf16(af[rt], wa[i * 4 + ks], acc[rt][h * 2 + i], 0, 0, 0);
            }
            // --- context part: k 128..255, A = Xprev then Xnext, weights pre-scaled 0.5 ---
            bfrag wc[8];                     // i(2) x ks(4)
            #pragma unroll
            for (int i = 0; i < 2; ++i)
                #pragma unroll
                for (int ks = 0; ks < 4; ++ks)
                    wc[i * 4 + ks] = *(const bfrag*)(wg1t + (size_t)(nAC + (h * 2 + i) * 16 + l16) * 256 + 128 + ks * 32 + lk8);
            __builtin_amdgcn_sched_barrier(0);
            #pragma unroll
            for (int ks = 0; ks < 4; ++ks) {
                bfrag ap[4], an[4];
                #pragma unroll
                for (int rt = 0; rt < 4; ++rt) {
                    ap[rt] = *(const bfrag*)&Xext[rt * 16 + l16][ks * 32 + lk8];
                    an[rt] = *(const bfrag*)&Xext[rt * 16 + l16 + 2][ks * 32 + lk8];
                }
                #pragma unroll
                for (int i = 0; i < 2; ++i)
                    #pragma unroll
                    for (int rt = 0; rt < 4; ++rt) {
                        acc[rt][h * 2 + i] = __builtin_amdgcn_mfma_f32_16x16x32_bf16(ap[rt], wc[i * 4 + ks], acc[rt][h * 2 + i], 0, 0, 0);
                        acc[rt][h * 2 + i] = __builtin_amdgcn_mfma_f32_16x16x32_bf16(an[rt], wc[i * 4 + ks], acc[rt][h * 2 + i], 0, 0, 0);
                    }
            }
        }
        __syncthreads();   // all waves done reading Hb (phase B) before overwrite
        #pragma unroll
        for (int cp2 = 0; cp2 < 2; ++cp2) {
            const float bga = bg1[nAC + (2 * cp2) * 16 + l16];
            const float bgb = bg1[nAC + (2 * cp2 + 1) * 16 + l16];
            #pragma unroll
            for (int rt = 0; rt < 4; ++rt)
                #pragma unroll
                for (int r = 0; r < 4; ++r) {
                    const float r0v = fmaxf(acc[rt][2 * cp2][r]     + bga, 0.f);
                    const float r1v = fmaxf(acc[rt][2 * cp2 + 1][r] + bgb, 0.f);
                    const unsigned p = pkbf(r0v, r1v);
                    Hb[rt * 16 + l4 + r][nAC + (2 * cp2) * 16 + l16]     = (u16)(p & 0xffffu);
                    Hb[rt * 16 + l4 + r][nAC + (2 * cp2 + 1) * 16 + l16] = (u16)(p >> 16);
                }
        }
    }
    __syncthreads();

    // ================= Phase D: G = R @ Wg2 + bg2 ; out = x + LR*sigmoid(G)*err =================
    {
        bfrag wb[16];
        #pragma unroll
        for (int ct = 0; ct < 2; ++ct)
            #pragma unroll
            for (int ks = 0; ks < 8; ++ks)
                wb[ct * 8 + ks] = *(const bfrag*)(wg2t + (size_t)(nBD + ct * 16 + l16) * 256 + ks * 32 + lk8);
        float cp[4][2][4];   // cur prefetch - flies under D's MFMAs
        #pragma unroll
        for (int rt = 0; rt < 4; ++rt)
            #pragma unroll
            for (int ct = 0; ct < 2; ++ct)
                #pragma unroll
                for (int r = 0; r < 4; ++r)
                    cp[rt][ct][r] = cur[(size_t)(g0 + rt * 16 + l4 + r) * DD + nBD + ct * 16 + l16];
        __builtin_amdgcn_sched_barrier(0);
        f32x4 acc[4][2];
        #pragma unroll
        for (int rt = 0; rt < 4; ++rt) { acc[rt][0] = zf; acc[rt][1] = zf; }
        #pragma unroll
        for (int ks = 0; ks < 8; ++ks) {
            bfrag af[4];
            #pragma unroll
            for (int rt = 0; rt < 4; ++rt)
                af[rt] = *(const bfrag*)&Hb[rt * 16 + l16][ks * 32 + lk8];
            #pragma unroll
            for (int ct = 0; ct < 2; ++ct)
                #pragma unroll
                for (int rt = 0; rt < 4; ++rt)
                    acc[rt][ct] = __builtin_amdgcn_mfma_f32_16x16x32_bf16(af[rt], wb[ct * 8 + ks], acc[rt][ct], 0, 0, 0);
        }
        #pragma unroll
        for (int ct = 0; ct < 2; ++ct) {
            const float bb = bg2[nBD + ct * 16 + l16];
            #pragma unroll
            for (int rt = 0; rt < 4; ++rt)
                #pragma unroll
                for (int r = 0; r < 4; ++r) {
                    const float z = acc[rt][ct][r] + bb;
                    const float gate = 1.f / (1.f + __expf(-z));
                    outp[(size_t)(g0 + rt * 16 + l4 + r) * DD + nBD + ct * 16 + l16] =
                        cp[rt][ct][r] + LRATE * gate * errv[rt][ct][r];
                }
        }
    }
}

extern "C" void kernel_launch(void* const* d_in, const int* in_sizes, int n_in,
                              void* d_out, int out_size, void* d_ws, size_t ws_size,
                              hipStream_t stream) {
    const float* emb = (const float*)d_in[0];
    const float* W1  = (const float*)d_in[1];
    const float* b1  = (const float*)d_in[2];
    const float* lng = (const float*)d_in[3];
    const float* lnb = (const float*)d_in[4];
    const float* W2  = (const float*)d_in[5];
    const float* b2  = (const float*)d_in[6];
    const float* Wg1 = (const float*)d_in[7];
    const float* bg1 = (const float*)d_in[8];
    const float* Wg2 = (const float*)d_in[9];
    const float* bg2 = (const float*)d_in[10];
    float* out = (float*)d_out;

    u16*   wsw  = (u16*)d_ws;                          // 320 KB bf16 transposed weights
    float* ping = (float*)((char*)d_ws + (1 << 20));   // 64 MB refined scratch

    const u16* w1t  = wsw;
    const u16* w2t  = wsw + 32768;
    const u16* wg1t = wsw + 65536;
    const u16* wg2t = wsw + 131072;

    prep_weights<<<640, 256, 0, stream>>>(W1, W2, Wg1, Wg2, wsw);

    const dim3 grid(NTOK / TM);
    const dim3 block(THREADS);
    // refined chain: emb -> out -> ping -> out -> ping -> out
    refine_iter<<<grid, block, 0, stream>>>(emb,  emb, out,  w1t, w2t, wg1t, wg2t, b1, lng, lnb, b2, bg1, bg2);
    refine_iter<<<grid, block, 0, stream>>>(out,  emb, ping, w1t, w2t, wg1t, wg2t, b1, lng, lnb, b2, bg1, bg2);
    refine_iter<<<grid, block, 0, stream>>>(ping, emb, out,  w1t, w2t, wg1t, wg2t, b1, lng, lnb, b2, bg1, bg2);
    refine_iter<<<grid, block, 0, stream>>>(out,  emb, ping, w1t, w2t, wg1t, wg2t, b1, lng, lnb, b2, bg1, bg2);
    refine_iter<<<grid, block, 0, stream>>>(ping, emb, out,  w1t, w2t, wg1t, wg2t, b1, lng, lnb, b2, bg1, bg2);
}

// Round 13
// 663.915 us; speedup vs baseline: 1.4577x; 1.4577x over previous
//
#include <hip/hip_runtime.h>
#include <hip/hip_bf16.h>

#define BB   16
#define SS   8192
#define DD   128
#define HH   256
#define NTOK (BB * SS)
#define TM   64
#define THREADS 256
#define LRATE 0.1f
#define EPSV  1e-5f
#define XST  136   // Xext stride in shorts (68 dw ≡ 4 mod 32, proven conflict-light)
#define HST  260   // Hb stride in shorts (130 dw ≡ 2 mod 32: frag reads 2-way (free), scatter ok)

typedef short  bfrag __attribute__((ext_vector_type(8)));   // 8 bf16 = 4 VGPR (MFMA A/B frag)
typedef float  f32x4 __attribute__((ext_vector_type(4)));   // MFMA C/D frag
typedef unsigned short u16;

__device__ __forceinline__ u16 f2bf(float x) {
    unsigned u = __float_as_uint(x);
    unsigned r = (u + 0x7FFFu + ((u >> 16) & 1u)) >> 16;   // RTN-even
    return (u16)r;
}

// packed 2xfloat -> 2xbf16 (v_cvt_pk_bf16_f32, RNE)
__device__ __forceinline__ unsigned pkbf(float lo, float hi) {
    __hip_bfloat162 h2 = __float22bfloat162_rn(make_float2(lo, hi));
    unsigned u; __builtin_memcpy(&u, &h2, 4); return u;
}

// ---- weight prep: fp32 [K][N] -> bf16 transposed [N][K] in ws ----
// layout (shorts): W1t[256][128] @0, W2t[128][256] @32768, Wg1t[256][256] @65536 (k>=128 half scaled by 0.5),
//                  Wg2t[128][256] @131072
__global__ void prep_weights(const float* __restrict__ W1, const float* __restrict__ W2,
                             const float* __restrict__ Wg1, const float* __restrict__ Wg2,
                             u16* __restrict__ wsw) {
    int i = blockIdx.x * 256 + threadIdx.x;   // 0 .. 163839
    if (i < 32768) { int n = i >> 7, k = i & 127; wsw[i] = f2bf(W1[k * 256 + n]); return; }
    i -= 32768;
    if (i < 32768) { int n = i >> 8, k = i & 255; wsw[32768 + n * 256 + k] = f2bf(W2[k * 128 + n]); return; }
    i -= 32768;
    if (i < 65536) {
        int n = i >> 8, k = i & 255;
        const float s = (k >= 128) ? 0.5f : 1.0f;            // fold context average into weights
        wsw[65536 + n * 256 + k] = f2bf(Wg1[k * 256 + n] * s);
        return;
    }
    i -= 65536;
    { int n = i >> 8, k = i & 255; wsw[131072 + n * 256 + k] = f2bf(Wg2[k * 128 + n]); }
}

__global__ __launch_bounds__(THREADS, 2)
void refine_iter(const float* __restrict__ cur, const float* __restrict__ emb,
                 float* __restrict__ outp,
                 const u16* __restrict__ w1t, const u16* __restrict__ w2t,
                 const u16* __restrict__ wg1t, const u16* __restrict__ wg2t,
                 const float* __restrict__ b1, const float* __restrict__ lng,
                 const float* __restrict__ lnb, const float* __restrict__ b2,
                 const float* __restrict__ bg1, const float* __restrict__ bg2)
{
    __shared__ __align__(16) u16 Xext[TM + 2][XST];  // rows g0-1 .. g0+64, bf16 (17.95 KB)
    __shared__ __align__(16) u16 Hb[TM][HST];        // H then R (33.28 KB)
    __shared__ float red1[TM][4];
    __shared__ float red2[TM][4];

    const int t    = threadIdx.x;
    const int g0   = blockIdx.x * TM;
    const int lane = t & 63;
    const int wid  = t >> 6;              // 4 waves; each owns ALL 64 rows x a column slice
    const int l16  = lane & 15;
    const int lk8  = (lane >> 4) * 8;     // k-offset within a 32-chunk
    const int l4   = (lane >> 4) * 4;     // D-frag row offset
    const int nAC  = wid * 64;            // A/C col slice (64 wide, ct 0..3)
    const int nBD  = wid * 32;            // B/D col slice (32 wide, ct 0..1)

    // ---- early prefetch: emb values needed by phase B (acc layout) ----
    float ep[4][2][4];
    #pragma unroll
    for (int rt = 0; rt < 4; ++rt)
        #pragma unroll
        for (int ct = 0; ct < 2; ++ct)
            #pragma unroll
            for (int r = 0; r < 4; ++r)
                ep[rt][ct][r] = emb[(size_t)(g0 + rt * 16 + l4 + r) * DD + nBD + ct * 16 + l16];

    // ---- stage Xext rows g0-1 .. g0+64 (fp32 -> bf16, packed cvt) ----
    {
        const int b13 = g0 & ~(SS - 1);   // batch base token
        const int s0  = g0 & (SS - 1);
        #pragma unroll
        for (int k = 0; k < 9; ++k) {
            const int f = t + k * THREADS;
            if (f < (TM + 2) * 32) {
                const int j = f >> 5;             // row 0..65
                const int o = (f & 31) * 4;
                int sraw = s0 + j - 1;
                const int s = (sraw < 0) ? 1 : ((sraw > SS - 1) ? (SS - 2) : sraw);
                const float4 xv = *(const float4*)(cur + (size_t)(b13 + s) * DD + o);
                uint2 xq; xq.x = pkbf(xv.x, xv.y); xq.y = pkbf(xv.z, xv.w);
                *(uint2*)&Xext[j][o] = xq;
            }
        }
    }
    __syncthreads();

    const f32x4 zf = {0.f, 0.f, 0.f, 0.f};
    float mu[4][4], rs[4][4];

    // ================= Phase A: Y1 = X @ W1 + b1  (64x256, K=128) =================
    {
        f32x4 acc[4][4];   // [rt][ct]
        #pragma unroll
        for (int rt = 0; rt < 4; ++rt)
            #pragma unroll
            for (int ct = 0; ct < 4; ++ct) acc[rt][ct] = zf;
        #pragma unroll
        for (int h = 0; h < 2; ++h) {        // ct-pairs
            bfrag wb[8];                     // i(2) x ks(4), batched
            #pragma unroll
            for (int i = 0; i < 2; ++i)
                #pragma unroll
                for (int ks = 0; ks < 4; ++ks)
                    wb[i * 4 + ks] = *(const bfrag*)(w1t + (size_t)(nAC + (h * 2 + i) * 16 + l16) * 128 + ks * 32 + lk8);
            __builtin_amdgcn_sched_barrier(0);
            #pragma unroll
            for (int ks = 0; ks < 4; ++ks) {
                bfrag af[4];
                #pragma unroll
                for (int rt = 0; rt < 4; ++rt)
                    af[rt] = *(const bfrag*)&Xext[rt * 16 + l16 + 1][ks * 32 + lk8];
                #pragma unroll
                for (int i = 0; i < 2; ++i)
                    #pragma unroll
                    for (int rt = 0; rt < 4; ++rt)
                        acc[rt][h * 2 + i] = __builtin_amdgcn_mfma_f32_16x16x32_bf16(af[rt], wb[i * 4 + ks], acc[rt][h * 2 + i], 0, 0, 0);
            }
        }
        // bias before LN stats
        #pragma unroll
        for (int ct = 0; ct < 4; ++ct) {
            const float bb = b1[nAC + ct * 16 + l16];
            #pragma unroll
            for (int rt = 0; rt < 4; ++rt)
                #pragma unroll
                for (int r = 0; r < 4; ++r) acc[rt][ct][r] += bb;
        }

        // ---- LN stats: 16-lane butterfly per row, cross-wave via red ----
        #pragma unroll
        for (int rt = 0; rt < 4; ++rt)
            #pragma unroll
            for (int r = 0; r < 4; ++r) {
                float a = 0.f, q = 0.f;
                #pragma unroll
                for (int ct = 0; ct < 4; ++ct) {
                    const float v = acc[rt][ct][r];
                    a += v; q += v * v;
                }
                #pragma unroll
                for (int m = 1; m <= 8; m <<= 1) {
                    a += __shfl_xor(a, m);
                    q += __shfl_xor(q, m);
                }
                if (l16 == 0) {
                    red1[rt * 16 + l4 + r][wid] = a;
                    red2[rt * 16 + l4 + r][wid] = q;
                }
            }
        __syncthreads();
        #pragma unroll
        for (int rt = 0; rt < 4; ++rt)
            #pragma unroll
            for (int r = 0; r < 4; ++r) {
                const int row = rt * 16 + l4 + r;
                const float4 s1v = *(const float4*)&red1[row][0];
                const float4 s2v = *(const float4*)&red2[row][0];
                const float s1 = s1v.x + s1v.y + s1v.z + s1v.w;
                const float s2 = s2v.x + s2v.y + s2v.z + s2v.w;
                const float m_ = s1 * (1.f / (float)HH);
                mu[rt][r] = m_;
                rs[rt][r] = rsqrtf(s2 * (1.f / (float)HH) - m_ * m_ + EPSV);
            }

        // ---- normalize + affine + relu -> Hb (bf16, packed cvt per ct-pair) ----
        #pragma unroll
        for (int cp2 = 0; cp2 < 2; ++cp2) {
            const float g0v = lng[nAC + (2 * cp2) * 16 + l16],     b0v = lnb[nAC + (2 * cp2) * 16 + l16];
            const float g1v = lng[nAC + (2 * cp2 + 1) * 16 + l16], b1v = lnb[nAC + (2 * cp2 + 1) * 16 + l16];
            #pragma unroll
            for (int rt = 0; rt < 4; ++rt)
                #pragma unroll
                for (int r = 0; r < 4; ++r) {
                    const float h0 = fmaxf((acc[rt][2 * cp2][r]     - mu[rt][r]) * rs[rt][r] * g0v + b0v, 0.f);
                    const float h1 = fmaxf((acc[rt][2 * cp2 + 1][r] - mu[rt][r]) * rs[rt][r] * g1v + b1v, 0.f);
                    const unsigned p = pkbf(h0, h1);
                    Hb[rt * 16 + l4 + r][nAC + (2 * cp2) * 16 + l16]     = (u16)(p & 0xffffu);
                    Hb[rt * 16 + l4 + r][nAC + (2 * cp2 + 1) * 16 + l16] = (u16)(p >> 16);
                }
        }
    }
    __syncthreads();

    // ================= Phase B: P = H @ W2 + b2 ; err = emb - P  (64x128, K=256) =================
    float errv[4][2][4];
    {
        f32x4 acc[4][2];
        #pragma unroll
        for (int rt = 0; rt < 4; ++rt) { acc[rt][0] = zf; acc[rt][1] = zf; }
        bfrag wb[16];                        // ct(2) x ks(8), batched
        #pragma unroll
        for (int ct = 0; ct < 2; ++ct)
            #pragma unroll
            for (int ks = 0; ks < 8; ++ks)
                wb[ct * 8 + ks] = *(const bfrag*)(w2t + (size_t)(nBD + ct * 16 + l16) * 256 + ks * 32 + lk8);
        __builtin_amdgcn_sched_barrier(0);
        #pragma unroll
        for (int ks = 0; ks < 8; ++ks) {
            bfrag af[4];
            #pragma unroll
            for (int rt = 0; rt < 4; ++rt)
                af[rt] = *(const bfrag*)&Hb[rt * 16 + l16][ks * 32 + lk8];
            #pragma unroll
            for (int ct = 0; ct < 2; ++ct)
                #pragma unroll
                for (int rt = 0; rt < 4; ++rt)
                    acc[rt][ct] = __builtin_amdgcn_mfma_f32_16x16x32_bf16(af[rt], wb[ct * 8 + ks], acc[rt][ct], 0, 0, 0);
        }
        #pragma unroll
        for (int ct = 0; ct < 2; ++ct) {
            const float bb = b2[nBD + ct * 16 + l16];
            #pragma unroll
            for (int rt = 0; rt < 4; ++rt)
                #pragma unroll
                for (int r = 0; r < 4; ++r)
                    errv[rt][ct][r] = ep[rt][ct][r] - (acc[rt][ct][r] + bb);
        }
    }

    // ===== Phase C: R = relu(X@Wg1a + Xprev@Wg1b' + Xnext@Wg1b' + bg1)  (Wg1b' pre-scaled 0.5) =====
    // low-pressure: one A-array and one weight batch live at a time
    {
        f32x4 acc[4][4];
        #pragma unroll
        for (int rt = 0; rt < 4; ++rt)
            #pragma unroll
            for (int ct = 0; ct < 4; ++ct) acc[rt][ct] = zf;
        #pragma unroll
        for (int h = 0; h < 2; ++h) {        // ct-pairs
            // --- X part: k 0..127 ---
            {
                bfrag wa[8];                 // i(2) x ks(4)
                #pragma unroll
                for (int i = 0; i < 2; ++i)
                    #pragma unroll
                    for (int ks = 0; ks < 4; ++ks)
                        wa[i * 4 + ks] = *(const bfrag*)(wg1t + (size_t)(nAC + (h * 2 + i) * 16 + l16) * 256 + ks * 32 + lk8);
                __builtin_amdgcn_sched_barrier(0);
                #pragma unroll
                for (int ks = 0; ks < 4; ++ks) {
                    bfrag af[4];
                    #pragma unroll
                    for (int rt = 0; rt < 4; ++rt)
                        af[rt] = *(const bfrag*)&Xext[rt * 16 + l16 + 1][ks * 32 + lk8];
                    #pragma unroll
                    for (int i = 0; i < 2; ++i)
                        #pragma unroll
                        for (int rt = 0; rt < 4; ++rt)
                            acc[rt][h * 2 + i] = __builtin_amdgcn_mfma_f32_16x16x32_bf16(af[rt], wa[i * 4 + ks], acc[rt][h * 2 + i], 0, 0, 0);
                }
            }
            // --- context part: k 128..255, A = Xprev then Xnext (sequential), weights pre-scaled 0.5 ---
            {
                bfrag wc[8];                 // i(2) x ks(4), shared by prev and next loops
                #pragma unroll
                for (int i = 0; i < 2; ++i)
                    #pragma unroll
                    for (int ks = 0; ks < 4; ++ks)
                        wc[i * 4 + ks] = *(const bfrag*)(wg1t + (size_t)(nAC + (h * 2 + i) * 16 + l16) * 256 + 128 + ks * 32 + lk8);
                __builtin_amdgcn_sched_barrier(0);
                #pragma unroll
                for (int ks = 0; ks < 4; ++ks) {
                    bfrag af[4];
                    #pragma unroll
                    for (int rt = 0; rt < 4; ++rt)
                        af[rt] = *(const bfrag*)&Xext[rt * 16 + l16][ks * 32 + lk8];       // prev
                    #pragma unroll
                    for (int i = 0; i < 2; ++i)
                        #pragma unroll
                        for (int rt = 0; rt < 4; ++rt)
                            acc[rt][h * 2 + i] = __builtin_amdgcn_mfma_f32_16x16x32_bf16(af[rt], wc[i * 4 + ks], acc[rt][h * 2 + i], 0, 0, 0);
                }
                #pragma unroll
                for (int ks = 0; ks < 4; ++ks) {
                    bfrag af[4];
                    #pragma unroll
                    for (int rt = 0; rt < 4; ++rt)
                        af[rt] = *(const bfrag*)&Xext[rt * 16 + l16 + 2][ks * 32 + lk8];   // next
                    #pragma unroll
                    for (int i = 0; i < 2; ++i)
                        #pragma unroll
                        for (int rt = 0; rt < 4; ++rt)
                            acc[rt][h * 2 + i] = __builtin_amdgcn_mfma_f32_16x16x32_bf16(af[rt], wc[i * 4 + ks], acc[rt][h * 2 + i], 0, 0, 0);
                }
            }
        }
        __syncthreads();   // all waves done reading Hb (phase B) before overwrite
        #pragma unroll
        for (int cp2 = 0; cp2 < 2; ++cp2) {
            const float bga = bg1[nAC + (2 * cp2) * 16 + l16];
            const float bgb = bg1[nAC + (2 * cp2 + 1) * 16 + l16];
            #pragma unroll
            for (int rt = 0; rt < 4; ++rt)
                #pragma unroll
                for (int r = 0; r < 4; ++r) {
                    const float r0v = fmaxf(acc[rt][2 * cp2][r]     + bga, 0.f);
                    const float r1v = fmaxf(acc[rt][2 * cp2 + 1][r] + bgb, 0.f);
                    const unsigned p = pkbf(r0v, r1v);
                    Hb[rt * 16 + l4 + r][nAC + (2 * cp2) * 16 + l16]     = (u16)(p & 0xffffu);
                    Hb[rt * 16 + l4 + r][nAC + (2 * cp2 + 1) * 16 + l16] = (u16)(p >> 16);
                }
        }
    }
    __syncthreads();

    // ================= Phase D: G = R @ Wg2 + bg2 ; out = x + LR*sigmoid(G)*err =================
    {
        bfrag wb[16];
        #pragma unroll
        for (int ct = 0; ct < 2; ++ct)
            #pragma unroll
            for (int ks = 0; ks < 8; ++ks)
                wb[ct * 8 + ks] = *(const bfrag*)(wg2t + (size_t)(nBD + ct * 16 + l16) * 256 + ks * 32 + lk8);
        float cp[4][2][4];   // cur prefetch - flies under D's MFMAs
        #pragma unroll
        for (int rt = 0; rt < 4; ++rt)
            #pragma unroll
            for (int ct = 0; ct < 2; ++ct)
                #pragma unroll
                for (int r = 0; r < 4; ++r)
                    cp[rt][ct][r] = cur[(size_t)(g0 + rt * 16 + l4 + r) * DD + nBD + ct * 16 + l16];
        __builtin_amdgcn_sched_barrier(0);
        f32x4 acc[4][2];
        #pragma unroll
        for (int rt = 0; rt < 4; ++rt) { acc[rt][0] = zf; acc[rt][1] = zf; }
        #pragma unroll
        for (int ks = 0; ks < 8; ++ks) {
            bfrag af[4];
            #pragma unroll
            for (int rt = 0; rt < 4; ++rt)
                af[rt] = *(const bfrag*)&Hb[rt * 16 + l16][ks * 32 + lk8];
            #pragma unroll
            for (int ct = 0; ct < 2; ++ct)
                #pragma unroll
                for (int rt = 0; rt < 4; ++rt)
                    acc[rt][ct] = __builtin_amdgcn_mfma_f32_16x16x32_bf16(af[rt], wb[ct * 8 + ks], acc[rt][ct], 0, 0, 0);
        }
        #pragma unroll
        for (int ct = 0; ct < 2; ++ct) {
            const float bb = bg2[nBD + ct * 16 + l16];
            #pragma unroll
            for (int rt = 0; rt < 4; ++rt)
                #pragma unroll
                for (int r = 0; r < 4; ++r) {
                    const float z = acc[rt][ct][r] + bb;
                    const float gate = 1.f / (1.f + __expf(-z));
                    outp[(size_t)(g0 + rt * 16 + l4 + r) * DD + nBD + ct * 16 + l16] =
                        cp[rt][ct][r] + LRATE * gate * errv[rt][ct][r];
                }
        }
    }
}

extern "C" void kernel_launch(void* const* d_in, const int* in_sizes, int n_in,
                              void* d_out, int out_size, void* d_ws, size_t ws_size,
                              hipStream_t stream) {
    const float* emb = (const float*)d_in[0];
    const float* W1  = (const float*)d_in[1];
    const float* b1  = (const float*)d_in[2];
    const float* lng = (const float*)d_in[3];
    const float* lnb = (const float*)d_in[4];
    const float* W2  = (const float*)d_in[5];
    const float* b2  = (const float*)d_in[6];
    const float* Wg1 = (const float*)d_in[7];
    const float* bg1 = (const float*)d_in[8];
    const float* Wg2 = (const float*)d_in[9];
    const float* bg2 = (const float*)d_in[10];
    float* out = (float*)d_out;

    u16*   wsw  = (u16*)d_ws;                          // 320 KB bf16 transposed weights
    float* ping = (float*)((char*)d_ws + (1 << 20));   // 64 MB refined scratch

    const u16* w1t  = wsw;
    const u16* w2t  = wsw + 32768;
    const u16* wg1t = wsw + 65536;
    const u16* wg2t = wsw + 131072;

    prep_weights<<<640, 256, 0, stream>>>(W1, W2, Wg1, Wg2, wsw);

    const dim3 grid(NTOK / TM);
    const dim3 block(THREADS);
    // refined chain: emb -> out -> ping -> out -> ping -> out
    refine_iter<<<grid, block, 0, stream>>>(emb,  emb, out,  w1t, w2t, wg1t, wg2t, b1, lng, lnb, b2, bg1, bg2);
    refine_iter<<<grid, block, 0, stream>>>(out,  emb, ping, w1t, w2t, wg1t, wg2t, b1, lng, lnb, b2, bg1, bg2);
    refine_iter<<<grid, block, 0, stream>>>(ping, emb, out,  w1t, w2t, wg1t, wg2t, b1, lng, lnb, b2, bg1, bg2);
    refine_iter<<<grid, block, 0, stream>>>(out,  emb, ping, w1t, w2t, wg1t, wg2t, b1, lng, lnb, b2, bg1, bg2);
    refine_iter<<<grid, block, 0, stream>>>(ping, emb, out,  w1t, w2t, wg1t, wg2t, b1, lng, lnb, b2, bg1, bg2);
}